// Round 9
// baseline (872.739 us; speedup 1.0000x reference)
//
#include <hip/hip_runtime.h>
#include <hip/hip_bf16.h>

typedef __attribute__((ext_vector_type(8))) short short8;   // 8 bf16 in 4 VGPRs
typedef __attribute__((ext_vector_type(4))) float f32x4;

#define N_HEAD 16
#define DMODEL 1024
#define LV 2048
#define LQ 2048
#define BATCH 2
#define HEAD_DIM 64

template <int N> struct IC { static constexpr int v = N; };

__device__ inline ushort f2bf(float f) {
    union { float f; unsigned u; } v; v.f = f;
    unsigned r = v.u + 0x7fffu + ((v.u >> 16) & 1u);   // RNE
    return (ushort)(r >> 16);
}
__device__ inline float bf2f(ushort h) {
    union { unsigned u; float f; } v; v.u = ((unsigned)h) << 16;
    return v.f;
}

// ---------------- cast f32 -> bf16 (same layout) ----------------
__global__ __launch_bounds__(256) void cast_bf16(const float* __restrict__ src,
                                                 ushort* __restrict__ dst, int n) {
    int i = (blockIdx.x * 256 + threadIdx.x) * 4;
    if (i < n) {
        float4 v = *(const float4*)(src + i);
        ushort4 o;
        o.x = f2bf(v.x); o.y = f2bf(v.y); o.z = f2bf(v.z); o.w = f2bf(v.w);
        *(ushort4*)(dst + i) = o;
    }
}

// ---------------- transpose + cast: src[z][R][C] f32 -> dst[z][C][R] bf16 ----
__global__ __launch_bounds__(256) void transpose_cast(const float* __restrict__ src,
                                                      ushort* __restrict__ dst,
                                                      int R, int C) {
    __shared__ float t[32][33];
    size_t zoff = (size_t)blockIdx.z * R * C;
    int c0 = blockIdx.x * 32, r0 = blockIdx.y * 32;
    int tx = threadIdx.x, ty = threadIdx.y;
#pragma unroll
    for (int i = 0; i < 4; ++i)
        t[ty + i * 8][tx] = src[zoff + (size_t)(r0 + ty + i * 8) * C + c0 + tx];
    __syncthreads();
#pragma unroll
    for (int i = 0; i < 4; ++i)
        dst[zoff + (size_t)(c0 + ty + i * 8) * R + r0 + tx] = f2bf(t[tx][ty + i * 8]);
}

// ------- 128x256 batched GEMM, 2 blocks/CU, COMPILER-SCHEDULED compute -------
// C[z] = (relu)(A[z] @ B[z]^T + bias).  Geometry identical to round 8 (BK=32,
// 3 bufs x 24KB = 72KB -> 2 blocks/CU, 8 waves 2Mx4N, wave-out 64x64).
// A/B vs round 8: compute is UNPINNED -- no sched_barrier / forced lgkmcnt(0) /
// setprio.  A-frags are read just-in-time between MFMA quads so the compiler
// emits fine-grained counted lgkmcnt (the m97 mechanism); ds_read latency
// hides under MFMA within the wave.  Counted vmcnt(3) + 1 barrier/step kept.
// Overwrite safety: every ds_read feeds an MFMA in-step; LDS returns in order,
// so the a[3]-consuming MFMA implies lgkmcnt==0 before the end-of-step barrier.
template <bool RELU>
__global__ __launch_bounds__(512, 4) void gemm128x256(
    const ushort* __restrict__ A, const ushort* __restrict__ B,
    ushort* __restrict__ Cout, const float* __restrict__ bias,
    int K,
    long sA_b, long sA_h, long sB_b, long sB_h, long sC_z, int ldc, long sBias_h)
{
    // 3 bufs x [A: 8 subtiles x 1KB | B: 16 subtiles x 1KB] = 3 x 24 KB
    __shared__ __align__(16) char smem[3 * 24576];

    const int z = blockIdx.z, b = z & 1, h = z >> 1;
    A += (size_t)b * sA_b + (size_t)h * sA_h;
    B += (size_t)b * sB_b + (size_t)h * sB_h;
    const float* biasp = bias ? bias + (size_t)h * sBias_h : nullptr;

    const int bm0 = blockIdx.y * 128;     // A rows
    const int bn0 = blockIdx.x * 256;     // B rows (C cols)
    const int T = threadIdx.x;
    const int lane = T & 63, wid = T >> 6;
    const int wr = wid >> 2, wc = wid & 3;          // wave -> (2 x 4) grid
    const int fr = lane & 15, fq = lane >> 4;
    const int laneoff = fr * 64 + ((fq * 16) ^ ((fr >> 3) << 5));   // swz read

    // staging: thread T owns LDS bytes [T*16,T*16+16) of each 8 KB slice;
    // global col pre-swizzled (involution) so linear LDS dest + swz read match.
    const int s_row = T >> 2;                                   // 0..127
    const int s_csw = ((T & 3) * 16) ^ (((T >> 5) & 1) << 5);   // pre-swz col byte
    const ushort* gA = A + (size_t)(bm0 + s_row) * K + (s_csw >> 1);
    const ushort* gB = B + (size_t)(bn0 + s_row) * K + (s_csw >> 1);

    const int nt = K >> 5;      // K-steps of 32 (32 or 64 here)

    // stage K-tile kt into buf sb: A 1 load, B 2 loads per thread
    auto stage = [&](int sb, int kt) {
        char* base = smem + sb * 24576;
        const ushort* srcA = gA + (size_t)kt * 32;
        __builtin_amdgcn_global_load_lds(
            (const __attribute__((address_space(1))) void*)srcA,
            (__attribute__((address_space(3))) void*)(base + (T << 4)), 16, 0, 0);
#pragma unroll
        for (int j = 0; j < 2; ++j) {
            const ushort* srcB = gB + (size_t)j * 128 * K + (size_t)kt * 32;
            __builtin_amdgcn_global_load_lds(
                (const __attribute__((address_space(1))) void*)srcB,
                (__attribute__((address_space(3))) void*)(base + 8192 + j * 8192 + (T << 4)),
                16, 0, 0);
        }
    };

    f32x4 acc[4][4];
#pragma unroll
    for (int m = 0; m < 4; ++m)
#pragma unroll
        for (int n = 0; n < 4; ++n)
#pragma unroll
            for (int j = 0; j < 4; ++j) acc[m][n][j] = 0.f;

    // one K-step; rb = read buf (t%3), sb = stage buf ((t+2)%3).
    // UNPINNED: compiler schedules ds_read <-> MFMA with counted lgkmcnt.
    auto step = [&](int t, int rb, int sb, auto DOST, auto VM) {
        const char* base = smem + rb * 24576;
        const char* pA = base + wr * 4096 + laneoff;
        const char* pB = base + 8192 + wc * 4096 + laneoff;
        if constexpr (decltype(DOST)::v) stage(sb, t + 2);   // issue early
        short8 bb[4];
#pragma unroll
        for (int n = 0; n < 4; ++n) bb[n] = *(const short8*)(pB + n * 1024);
        short8 a[4];
        a[0] = *(const short8*)(pA);
#pragma unroll
        for (int m = 0; m < 4; ++m) {
            if (m < 3) a[m + 1] = *(const short8*)(pA + (m + 1) * 1024);
#pragma unroll
            for (int n = 0; n < 4; ++n)
                acc[m][n] = __builtin_amdgcn_mfma_f32_16x16x32_bf16(
                    a[m], bb[n], acc[m][n], 0, 0, 0);
        }
        constexpr int vm = decltype(VM)::v;
        if constexpr (vm == 3) asm volatile("s_waitcnt vmcnt(3)" ::: "memory");
        else if constexpr (vm == 0) asm volatile("s_waitcnt vmcnt(0)" ::: "memory");
        if constexpr (vm >= 0) asm volatile("s_barrier" ::: "memory");
    };

    // prologue: stage tiles 0,1 into bufs 0,1; wait tile 0 (outstanding 6->3)
    stage(0, 0); stage(1, 1);
    asm volatile("s_waitcnt vmcnt(3)" ::: "memory");
    asm volatile("s_barrier" ::: "memory");

    int rb = 0, sb = 2;
    for (int t = 0; t < nt - 2; ++t) {
        step(t, rb, sb, IC<1>{}, IC<3>{});
        rb = (rb == 2) ? 0 : rb + 1;
        sb = (sb == 2) ? 0 : sb + 1;
    }
    step(nt - 2, rb, sb, IC<0>{}, IC<0>{});     // drain last stage
    rb = (rb == 2) ? 0 : rb + 1;
    step(nt - 1, rb, sb, IC<0>{}, IC<-1>{});    // last MFMA, no barrier

    // epilogue: C[row = m*16 + fq*4 + j][col = n*16 + fr]  (m89/m91-verified)
    ushort* C = Cout + (size_t)z * sC_z;
    const int row0 = bm0 + wr * 64;
    const int col0 = bn0 + wc * 64;
#pragma unroll
    for (int n = 0; n < 4; ++n) {
        const int c = col0 + n * 16 + fr;
        const float bvv = biasp ? biasp[c] : 0.f;
#pragma unroll
        for (int m = 0; m < 4; ++m) {
            const int r = row0 + m * 16 + fq * 4;
#pragma unroll
            for (int j = 0; j < 4; ++j) {
                float val = acc[m][n][j] + bvv;
                if (RELU) val = fmaxf(val, 0.f);
                C[(size_t)(r + j) * ldc + c] = f2bf(val);
            }
        }
    }
}

// ---------------- in-place LayerNorm over last dim (1024) of agg bf16 --------
__global__ __launch_bounds__(256) void ln_kernel(ushort* __restrict__ agg,
                                                 const float* __restrict__ gamma,
                                                 const float* __restrict__ beta) {
    const int wid = threadIdx.x >> 6, lane = threadIdx.x & 63;
    const size_t row = (size_t)blockIdx.x * 4 + wid;
    const int h = (int)(row >> 12);
    ushort* p = agg + row * 1024 + lane * 16;
    short8 r0 = *(const short8*)p;
    short8 r1 = *(const short8*)(p + 8);
    float x[16];
#pragma unroll
    for (int j = 0; j < 8; ++j) { x[j] = bf2f((ushort)r0[j]); x[8 + j] = bf2f((ushort)r1[j]); }
    float s = 0.f, s2 = 0.f;
#pragma unroll
    for (int j = 0; j < 16; ++j) { s += x[j]; s2 += x[j] * x[j]; }
    for (int o = 1; o < 64; o <<= 1) {
        s  += __shfl_xor(s,  o, 64);
        s2 += __shfl_xor(s2, o, 64);
    }
    float mu  = s * (1.0f / 1024.0f);
    float var = s2 * (1.0f / 1024.0f) - mu * mu;
    float rs  = rsqrtf(fmaxf(var, 0.f) + 1e-5f);
    const float* g  = gamma + (size_t)h * 1024 + lane * 16;
    const float* bt = beta  + (size_t)h * 1024 + lane * 16;
    short8 o0, o1;
#pragma unroll
    for (int j = 0; j < 8; ++j) {
        o0[j] = (short)f2bf((x[j]     - mu) * rs * g[j]     + bt[j]);
        o1[j] = (short)f2bf((x[8 + j] - mu) * rs * g[8 + j] + bt[8 + j]);
    }
    *(short8*)p = o0;
    *(short8*)(p + 8) = o1;
}

// ---------------- projection: out[b][q][(h0+h)*64+e] = normed[z] @ WpT[h]^T + bp
__global__ __launch_bounds__(256) void proj_kernel(const ushort* __restrict__ normed,
                                                   const ushort* __restrict__ WpT,
                                                   const float* __restrict__ bp,
                                                   float* __restrict__ out,
                                                   int h_base) {
    const int z = blockIdx.y, b = z & 1, h = z >> 1;
    const int hg = h_base + h;
    const int wid = threadIdx.x >> 6, lane = threadIdx.x & 63;
    const int fr = lane & 15, fq = lane >> 4;
    const int m0 = (blockIdx.x * 4 + wid) * 16;

    const ushort* Abase = normed + ((size_t)z * 2048 + m0 + fr) * 1024 + fq * 8;
    const ushort* Bbase = WpT + (size_t)hg * 64 * 1024 + (size_t)fr * 1024 + fq * 8;

    f32x4 acc[4];
#pragma unroll
    for (int n = 0; n < 4; ++n)
#pragma unroll
        for (int j = 0; j < 4; ++j) acc[n][j] = 0.f;

    for (int kt = 0; kt < 32; ++kt) {
        short8 a = *(const short8*)(Abase + kt * 32);
#pragma unroll
        for (int n = 0; n < 4; ++n) {
            short8 bb = *(const short8*)(Bbase + n * 16 * 1024 + kt * 32);
            acc[n] = __builtin_amdgcn_mfma_f32_16x16x32_bf16(a, bb, acc[n], 0, 0, 0);
        }
    }
#pragma unroll
    for (int n = 0; n < 4; ++n) {
        int c = hg * 64 + n * 16 + fr;
        float bvv = bp[hg * 64 + n * 16 + fr];
#pragma unroll
        for (int j = 0; j < 4; ++j)
            out[(size_t)b * 2048 * 1024 + (size_t)(m0 + fq * 4 + j) * 1024 + c] =
                acc[n][j] + bvv;
    }
}

extern "C" void kernel_launch(void* const* d_in, const int* in_sizes, int n_in,
                              void* d_out, int out_size, void* d_ws, size_t ws_size,
                              hipStream_t stream) {
    const float* v     = (const float*)d_in[0];
    const float* q     = (const float*)d_in[1];
    const float* Wa    = (const float*)d_in[2];
    const float* ba    = (const float*)d_in[3];
    const float* gamma = (const float*)d_in[4];
    const float* beta  = (const float*)d_in[5];
    const float* Wp    = (const float*)d_in[6];
    const float* bp    = (const float*)d_in[7];
    float* out = (float*)d_out;

    const size_t MB = 1ull << 20;
    char* ws = (char*)d_ws;
    ushort* qbf = (ushort*)(ws);                 //  8 MiB
    ushort* vT  = (ushort*)(ws + 8 * MB);        //  8 MiB
    ushort* WpT = (ushort*)(ws + 16 * MB);       //  2 MiB
    int NH = 1;
    {
        const int cands[5] = {16, 8, 4, 2, 1};
        for (int i = 0; i < 5; ++i) {
            if ((size_t)(18 + 28 * cands[i]) * MB <= ws_size) { NH = cands[i]; break; }
        }
    }
    ushort* WaT_c  = (ushort*)(ws + 18 * MB);
    ushort* attn_c = (ushort*)(ws + (18 + (size_t)4 * NH) * MB);
    ushort* agg_c  = (ushort*)(ws + (18 + (size_t)20 * NH) * MB);

    dim3 tb(32, 8);
    cast_bf16<<<4096, 256, 0, stream>>>(q, qbf, BATCH * LQ * DMODEL);
    transpose_cast<<<dim3(DMODEL / 32, LV / 32, BATCH), tb, 0, stream>>>(v, vT, LV, DMODEL);
    transpose_cast<<<dim3(HEAD_DIM / 32, DMODEL / 32, N_HEAD), tb, 0, stream>>>(Wp, WpT, DMODEL, HEAD_DIM);

    for (int h0 = 0; h0 < N_HEAD; h0 += NH) {
        transpose_cast<<<dim3(LV / 32, DMODEL / 32, NH), tb, 0, stream>>>(
            Wa + (size_t)h0 * DMODEL * LV, WaT_c, DMODEL, LV);

        // GEMM1: attn[z] = relu(q[b] @ WaT[h]^T + ba[h0+h]), M=2048 N=2048 K=1024
        gemm128x256<true><<<dim3(LV / 256, LQ / 128, NH * 2), 512, 0, stream>>>(
            qbf, WaT_c, attn_c, ba + (size_t)h0 * LV, DMODEL,
            (long)LQ * DMODEL, 0L,
            0L, (long)LV * DMODEL,
            (long)LQ * LV, LV, (long)LV);

        // GEMM2: agg[z] = attn[z] @ vT[b]^T, M=2048 N=1024 K=2048
        gemm128x256<false><<<dim3(DMODEL / 256, LQ / 128, NH * 2), 512, 0, stream>>>(
            attn_c, vT, agg_c, nullptr, LV,
            (long)LQ * LV, (long)2 * LQ * LV,
            (long)DMODEL * LV, 0L,
            (long)LQ * DMODEL, DMODEL, 0L);

        ln_kernel<<<(NH * 2 * LQ) / 4, 256, 0, stream>>>(
            agg_c, gamma + (size_t)h0 * DMODEL, beta + (size_t)h0 * DMODEL);

        proj_kernel<<<dim3(LQ / 64, NH * 2), 256, 0, stream>>>(
            agg_c, WpT, bp, out, h0);
    }
}

// Round 10
// 754.643 us; speedup vs baseline: 1.1565x; 1.1565x over previous
//
#include <hip/hip_runtime.h>
#include <hip/hip_bf16.h>

typedef __attribute__((ext_vector_type(8))) short short8;   // 8 bf16 in 4 VGPRs
typedef __attribute__((ext_vector_type(4))) float f32x4;

#define N_HEAD 16
#define DMODEL 1024
#define LV 2048
#define LQ 2048
#define BATCH 2
#define HEAD_DIM 64

template <int N> struct IC { static constexpr int v = N; };

__device__ inline ushort f2bf(float f) {
    union { float f; unsigned u; } v; v.f = f;
    unsigned r = v.u + 0x7fffu + ((v.u >> 16) & 1u);   // RNE
    return (ushort)(r >> 16);
}
__device__ inline float bf2f(ushort h) {
    union { unsigned u; float f; } v; v.u = ((unsigned)h) << 16;
    return v.f;
}

// ---------------- cast f32 -> bf16 (same layout) ----------------
__global__ __launch_bounds__(256) void cast_bf16(const float* __restrict__ src,
                                                 ushort* __restrict__ dst, int n) {
    int i = (blockIdx.x * 256 + threadIdx.x) * 4;
    if (i < n) {
        float4 v = *(const float4*)(src + i);
        ushort4 o;
        o.x = f2bf(v.x); o.y = f2bf(v.y); o.z = f2bf(v.z); o.w = f2bf(v.w);
        *(ushort4*)(dst + i) = o;
    }
}

// ---------------- transpose + cast: src[z][R][C] f32 -> dst[z][C][R] bf16 ----
__global__ __launch_bounds__(256) void transpose_cast(const float* __restrict__ src,
                                                      ushort* __restrict__ dst,
                                                      int R, int C) {
    __shared__ float t[32][33];
    size_t zoff = (size_t)blockIdx.z * R * C;
    int c0 = blockIdx.x * 32, r0 = blockIdx.y * 32;
    int tx = threadIdx.x, ty = threadIdx.y;
#pragma unroll
    for (int i = 0; i < 4; ++i)
        t[ty + i * 8][tx] = src[zoff + (size_t)(r0 + ty + i * 8) * C + c0 + tx];
    __syncthreads();
#pragma unroll
    for (int i = 0; i < 4; ++i)
        dst[zoff + (size_t)(c0 + ty + i * 8) * R + r0 + tx] = f2bf(t[tx][ty + i * 8]);
}

// ------- 128x256 batched GEMM (r8 core) + XCD z-chunk swizzle + full-line C --
// C[z] = (relu)(A[z] @ B[z]^T + bias).  BK=32, 3 bufs x 24KB = 72KB (2 blk/CU),
// 8 waves 2Mx4N, wave-out 64x64.  K-loop identical to round 8 (best measured).
// NEW: (a) 1D grid with bijective XCD swizzle -- each XCD owns a contiguous
// (z, bm, bn) chunk so A/B panels stay L2-local (T1); (b) epilogue stages the
// 64x64 bf16 wave-tile in LDS and writes 16 B/lane full-line stores, removing
// the 2x partial-sector write-amp + write-allocate RMW fetch seen in r8/r9.
// LNBN: log2(#bn blocks); ZSH: log2(bn*bm blocks per z).
template <bool RELU, int LNBN, int ZSH>
__global__ __launch_bounds__(512, 4) void gemm128x256(
    const ushort* __restrict__ A, const ushort* __restrict__ B,
    ushort* __restrict__ Cout, const float* __restrict__ bias,
    int K,
    long sA_b, long sA_h, long sB_b, long sB_h, long sC_z, int ldc, long sBias_h)
{
    // K-loop: 3 bufs x [A: 8KB | B: 16KB] = 72 KB.  Epilogue reuses as
    // 8 waves x (64 rows x 144 B) = 72 KB exactly.
    __shared__ __align__(16) char smem[3 * 24576];

    // bijective XCD swizzle (nwg % 8 == 0 always: nwg = 128*z or 64*z)
    const int gid = blockIdx.x;
    const int per = (int)gridDim.x >> 3;
    const int w = (gid & 7) * per + (gid >> 3);
    const int z = w >> ZSH;
    const int rem = w & ((1 << ZSH) - 1);
    const int bm0 = (rem >> LNBN) * 128;               // A rows
    const int bn0 = (rem & ((1 << LNBN) - 1)) * 256;   // B rows (C cols)

    const int b = z & 1, h = z >> 1;
    A += (size_t)b * sA_b + (size_t)h * sA_h;
    B += (size_t)b * sB_b + (size_t)h * sB_h;
    const float* biasp = bias ? bias + (size_t)h * sBias_h : nullptr;

    const int T = threadIdx.x;
    const int lane = T & 63, wid = T >> 6;
    const int wr = wid >> 2, wc = wid & 3;          // wave -> (2 x 4) grid
    const int fr = lane & 15, fq = lane >> 4;
    const int laneoff = fr * 64 + ((fq * 16) ^ ((fr >> 3) << 5));   // swz read

    // staging: thread T owns LDS bytes [T*16,T*16+16) of each 8 KB slice;
    // global col pre-swizzled (involution) so linear LDS dest + swz read match.
    const int s_row = T >> 2;                                   // 0..127
    const int s_csw = ((T & 3) * 16) ^ (((T >> 5) & 1) << 5);   // pre-swz col byte
    const ushort* gA = A + (size_t)(bm0 + s_row) * K + (s_csw >> 1);
    const ushort* gB = B + (size_t)(bn0 + s_row) * K + (s_csw >> 1);

    const int nt = K >> 5;      // K-steps of 32

    auto stage = [&](int sb, int kt) {
        char* base = smem + sb * 24576;
        const ushort* srcA = gA + (size_t)kt * 32;
        __builtin_amdgcn_global_load_lds(
            (const __attribute__((address_space(1))) void*)srcA,
            (__attribute__((address_space(3))) void*)(base + (T << 4)), 16, 0, 0);
#pragma unroll
        for (int j = 0; j < 2; ++j) {
            const ushort* srcB = gB + (size_t)j * 128 * K + (size_t)kt * 32;
            __builtin_amdgcn_global_load_lds(
                (const __attribute__((address_space(1))) void*)srcB,
                (__attribute__((address_space(3))) void*)(base + 8192 + j * 8192 + (T << 4)),
                16, 0, 0);
        }
    };

    f32x4 acc[4][4];
#pragma unroll
    for (int m = 0; m < 4; ++m)
#pragma unroll
        for (int n = 0; n < 4; ++n)
#pragma unroll
            for (int j = 0; j < 4; ++j) acc[m][n][j] = 0.f;

    // one K-step (identical to round 8's best)
    auto step = [&](int t, int rb, int sb, auto DOST, auto VM) {
        const char* base = smem + rb * 24576;
        const char* pA = base + wr * 4096 + laneoff;
        const char* pB = base + 8192 + wc * 4096 + laneoff;
        short8 a[4], bb[4];
#pragma unroll
        for (int m = 0; m < 4; ++m) a[m] = *(const short8*)(pA + m * 1024);
#pragma unroll
        for (int n = 0; n < 4; ++n) bb[n] = *(const short8*)(pB + n * 1024);
        if constexpr (decltype(DOST)::v) stage(sb, t + 2);
        asm volatile("s_waitcnt lgkmcnt(0)" ::: "memory");
        __builtin_amdgcn_sched_barrier(0);
        __builtin_amdgcn_s_setprio(1);
#pragma unroll
        for (int m = 0; m < 4; ++m)
#pragma unroll
            for (int n = 0; n < 4; ++n)
                acc[m][n] = __builtin_amdgcn_mfma_f32_16x16x32_bf16(
                    a[m], bb[n], acc[m][n], 0, 0, 0);
        __builtin_amdgcn_s_setprio(0);
        __builtin_amdgcn_sched_barrier(0);
        constexpr int vm = decltype(VM)::v;
        if constexpr (vm == 3) asm volatile("s_waitcnt vmcnt(3)" ::: "memory");
        else if constexpr (vm == 0) asm volatile("s_waitcnt vmcnt(0)" ::: "memory");
        if constexpr (vm >= 0) asm volatile("s_barrier" ::: "memory");
    };

    // prologue: stage tiles 0,1 into bufs 0,1; wait tile 0 (outstanding 6->3)
    stage(0, 0); stage(1, 1);
    asm volatile("s_waitcnt vmcnt(3)" ::: "memory");
    asm volatile("s_barrier" ::: "memory");

    int rb = 0, sb = 2;
    for (int t = 0; t < nt - 2; ++t) {
        step(t, rb, sb, IC<1>{}, IC<3>{});
        rb = (rb == 2) ? 0 : rb + 1;
        sb = (sb == 2) ? 0 : sb + 1;
    }
    step(nt - 2, rb, sb, IC<0>{}, IC<0>{});     // drain last stage
    rb = (rb == 2) ? 0 : rb + 1;
    step(nt - 1, rb, sb, IC<0>{}, IC<-1>{});    // last MFMA, no barrier

    // ---- epilogue: LDS repack -> full-line 16 B/lane stores ----
    // (C layout per frag: row = m*16 + fq*4 + j, col = n*16 + fr; m89/m91)
    asm volatile("s_waitcnt vmcnt(0) lgkmcnt(0)" ::: "memory");
    __builtin_amdgcn_s_barrier();              // all waves done with K-loop LDS
    char* eb = smem + wid * 9216;              // 64 rows x 144 B (16B-aligned rows)
    const int row0 = bm0 + wr * 64;
    const int col0 = bn0 + wc * 64;
#pragma unroll
    for (int n = 0; n < 4; ++n) {
        const float bvv = biasp ? biasp[col0 + n * 16 + fr] : 0.f;
#pragma unroll
        for (int m = 0; m < 4; ++m) {
#pragma unroll
            for (int j = 0; j < 4; ++j) {
                float val = acc[m][n][j] + bvv;
                if (RELU) val = fmaxf(val, 0.f);
                *(ushort*)(eb + (m * 16 + fq * 4 + j) * 144 + (n * 16 + fr) * 2) = f2bf(val);
            }
        }
    }
    asm volatile("s_waitcnt lgkmcnt(0)" ::: "memory");   // per-wave region: no barrier
    ushort* C = Cout + (size_t)z * sC_z;
    const int rl = lane >> 3, cb = lane & 7;
#pragma unroll
    for (int i = 0; i < 8; ++i) {
        short8 vv = *(const short8*)(eb + (i * 8 + rl) * 144 + cb * 16);
        *(short8*)(C + (size_t)(row0 + i * 8 + rl) * ldc + col0 + cb * 8) = vv;
    }
}

// -------- fused LayerNorm + projection:  out = LN(agg) @ WpT^T + bp ----------
// Per wave: 16 q-rows.  Pass 1: row mean/var (lane sums its 256 elems, 2-step
// shfl over the 4 fq-lanes sharing a row).  Pass 2: re-read (L2-hot), normalize
// in-register, feed MFMA A-frags directly.  agg never re-written to HBM.
__global__ __launch_bounds__(256) void lnproj_kernel(const ushort* __restrict__ agg,
                                                     const ushort* __restrict__ WpT,
                                                     const float* __restrict__ gamma,
                                                     const float* __restrict__ beta,
                                                     const float* __restrict__ bp,
                                                     float* __restrict__ out,
                                                     int h_base) {
    const int z = blockIdx.y, b = z & 1, hg = h_base + (z >> 1);
    const int wid = threadIdx.x >> 6, lane = threadIdx.x & 63;
    const int fr = lane & 15, fq = lane >> 4;
    const int m0 = (blockIdx.x * 4 + wid) * 16;

    const ushort* Arow = agg + ((size_t)z * 2048 + m0 + fr) * 1024 + fq * 8;

    // pass 1: stats for row m0+fr
    float s = 0.f, s2 = 0.f;
    for (int kt = 0; kt < 32; ++kt) {
        short8 a = *(const short8*)(Arow + kt * 32);
#pragma unroll
        for (int j = 0; j < 8; ++j) { float x = bf2f((ushort)a[j]); s += x; s2 += x * x; }
    }
    s  += __shfl_xor(s, 16, 64);  s2 += __shfl_xor(s2, 16, 64);
    s  += __shfl_xor(s, 32, 64);  s2 += __shfl_xor(s2, 32, 64);
    const float mu  = s * (1.0f / 1024.0f);
    const float var = s2 * (1.0f / 1024.0f) - mu * mu;
    const float rs  = rsqrtf(fmaxf(var, 0.f) + 1e-5f);

    const ushort* Bbase = WpT + (size_t)hg * 64 * 1024 + (size_t)fr * 1024 + fq * 8;
    const float* gp = gamma + (size_t)hg * 1024 + fq * 8;
    const float* bt = beta  + (size_t)hg * 1024 + fq * 8;

    f32x4 acc[4];
#pragma unroll
    for (int n = 0; n < 4; ++n)
#pragma unroll
        for (int j = 0; j < 4; ++j) acc[n][j] = 0.f;

    for (int kt = 0; kt < 32; ++kt) {
        short8 a = *(const short8*)(Arow + kt * 32);
        float4 g0 = *(const float4*)(gp + kt * 32);
        float4 g1 = *(const float4*)(gp + kt * 32 + 4);
        float4 b0 = *(const float4*)(bt + kt * 32);
        float4 b1 = *(const float4*)(bt + kt * 32 + 4);
        const float gg[8] = {g0.x, g0.y, g0.z, g0.w, g1.x, g1.y, g1.z, g1.w};
        const float bb_[8] = {b0.x, b0.y, b0.z, b0.w, b1.x, b1.y, b1.z, b1.w};
        short8 an;
#pragma unroll
        for (int j = 0; j < 8; ++j) {
            float xn = (bf2f((ushort)a[j]) - mu) * rs * gg[j] + bb_[j];
            an[j] = (short)f2bf(xn);
        }
#pragma unroll
        for (int n = 0; n < 4; ++n) {
            short8 wv = *(const short8*)(Bbase + n * 16 * 1024 + kt * 32);
            acc[n] = __builtin_amdgcn_mfma_f32_16x16x32_bf16(an, wv, acc[n], 0, 0, 0);
        }
    }
#pragma unroll
    for (int n = 0; n < 4; ++n) {
        const int c = hg * 64 + n * 16 + fr;
        const float bvv = bp[c];
#pragma unroll
        for (int j = 0; j < 4; ++j)
            out[(size_t)b * 2048 * 1024 + (size_t)(m0 + fq * 4 + j) * 1024 + c] =
                acc[n][j] + bvv;
    }
}

extern "C" void kernel_launch(void* const* d_in, const int* in_sizes, int n_in,
                              void* d_out, int out_size, void* d_ws, size_t ws_size,
                              hipStream_t stream) {
    const float* v     = (const float*)d_in[0];
    const float* q     = (const float*)d_in[1];
    const float* Wa    = (const float*)d_in[2];
    const float* ba    = (const float*)d_in[3];
    const float* gamma = (const float*)d_in[4];
    const float* beta  = (const float*)d_in[5];
    const float* Wp    = (const float*)d_in[6];
    const float* bp    = (const float*)d_in[7];
    float* out = (float*)d_out;

    const size_t MB = 1ull << 20;
    char* ws = (char*)d_ws;
    ushort* qbf = (ushort*)(ws);                 //  8 MiB
    ushort* vT  = (ushort*)(ws + 8 * MB);        //  8 MiB
    ushort* WpT = (ushort*)(ws + 16 * MB);       //  2 MiB
    int NH = 1;
    {
        const int cands[5] = {16, 8, 4, 2, 1};
        for (int i = 0; i < 5; ++i) {
            if ((size_t)(18 + 28 * cands[i]) * MB <= ws_size) { NH = cands[i]; break; }
        }
    }
    ushort* WaT_c  = (ushort*)(ws + 18 * MB);
    ushort* attn_c = (ushort*)(ws + (18 + (size_t)4 * NH) * MB);
    ushort* agg_c  = (ushort*)(ws + (18 + (size_t)20 * NH) * MB);

    dim3 tb(32, 8);
    cast_bf16<<<4096, 256, 0, stream>>>(q, qbf, BATCH * LQ * DMODEL);
    transpose_cast<<<dim3(DMODEL / 32, LV / 32, BATCH), tb, 0, stream>>>(v, vT, LV, DMODEL);
    transpose_cast<<<dim3(HEAD_DIM / 32, DMODEL / 32, N_HEAD), tb, 0, stream>>>(Wp, WpT, DMODEL, HEAD_DIM);

    for (int h0 = 0; h0 < N_HEAD; h0 += NH) {
        transpose_cast<<<dim3(LV / 32, DMODEL / 32, NH), tb, 0, stream>>>(
            Wa + (size_t)h0 * DMODEL * LV, WaT_c, DMODEL, LV);

        // GEMM1: attn[z] = relu(q[b] @ WaT[h]^T + ba[h0+h]), M=2048 N=2048 K=1024
        // grid: 8 bn x 16 bm x z  (1D, XCD-swizzled; 128 = 1<<7 blocks/z)
        gemm128x256<true, 3, 7><<<128 * NH * 2, 512, 0, stream>>>(
            qbf, WaT_c, attn_c, ba + (size_t)h0 * LV, DMODEL,
            (long)LQ * DMODEL, 0L,
            0L, (long)LV * DMODEL,
            (long)LQ * LV, LV, (long)LV);

        // GEMM2: agg[z] = attn[z] @ vT[b]^T, M=2048 N=1024 K=2048
        // grid: 4 bn x 16 bm x z  (64 = 1<<6 blocks/z)
        gemm128x256<false, 2, 6><<<64 * NH * 2, 512, 0, stream>>>(
            attn_c, vT, agg_c, nullptr, LV,
            (long)LQ * LV, (long)2 * LQ * LV,
            (long)DMODEL * LV, 0L,
            (long)LQ * DMODEL, DMODEL, 0L);

        // fused LayerNorm + projection + head concat -> d_out (f32)
        lnproj_kernel<<<dim3(LQ / 64, NH * 2), 256, 0, stream>>>(
            agg_c, WpT, gamma, beta, bp, out, h0);
    }
}

// Round 11
// 713.648 us; speedup vs baseline: 1.2229x; 1.0574x over previous
//
#include <hip/hip_runtime.h>
#include <hip/hip_bf16.h>

typedef __attribute__((ext_vector_type(8))) short short8;   // 8 bf16 in 4 VGPRs
typedef __attribute__((ext_vector_type(4))) float f32x4;

#define N_HEAD 16
#define DMODEL 1024
#define LV 2048
#define LQ 2048
#define BATCH 2
#define HEAD_DIM 64

template <int N> struct IC { static constexpr int v = N; };

__device__ inline ushort f2bf(float f) {
    union { float f; unsigned u; } v; v.f = f;
    unsigned r = v.u + 0x7fffu + ((v.u >> 16) & 1u);   // RNE
    return (ushort)(r >> 16);
}
__device__ inline float bf2f(ushort h) {
    union { unsigned u; float f; } v; v.u = ((unsigned)h) << 16;
    return v.f;
}

// ---------------- cast f32 -> bf16 (same layout) ----------------
__global__ __launch_bounds__(256) void cast_bf16(const float* __restrict__ src,
                                                 ushort* __restrict__ dst, int n) {
    int i = (blockIdx.x * 256 + threadIdx.x) * 4;
    if (i < n) {
        float4 v = *(const float4*)(src + i);
        ushort4 o;
        o.x = f2bf(v.x); o.y = f2bf(v.y); o.z = f2bf(v.z); o.w = f2bf(v.w);
        *(ushort4*)(dst + i) = o;
    }
}

// ---------------- transpose + cast: src[z][R][C] f32 -> dst[z][C][R] bf16 ----
__global__ __launch_bounds__(256) void transpose_cast(const float* __restrict__ src,
                                                      ushort* __restrict__ dst,
                                                      int R, int C) {
    __shared__ float t[32][33];
    size_t zoff = (size_t)blockIdx.z * R * C;
    int c0 = blockIdx.x * 32, r0 = blockIdx.y * 32;
    int tx = threadIdx.x, ty = threadIdx.y;
#pragma unroll
    for (int i = 0; i < 4; ++i)
        t[ty + i * 8][tx] = src[zoff + (size_t)(r0 + ty + i * 8) * C + c0 + tx];
    __syncthreads();
#pragma unroll
    for (int i = 0; i < 4; ++i)
        dst[zoff + (size_t)(c0 + ty + i * 8) * R + r0 + tx] = f2bf(t[tx][ty + i * 8]);
}

// ------- 128x256 batched GEMM, 4 waves x (128x64), 2 blocks/CU ---------------
// C[z] = (relu)(A[z] @ B[z]^T + bias).  BK=32, 3 bufs x 24KB = 72KB.
// vs r10: wave tile 64x64 -> 128x64 (12 ds_read_b128 per 32 MFMA, -25% LDS
// read traffic -- the binding pipe at 67% busy in r10); block = 256 thr,
// __launch_bounds__(256,2) -> 2 blocks/CU, 8 waves/CU.  K-loop schedule,
// swizzle, full-line epilogue, counted vmcnt identical to r10.
// Ordering: BMFAST=1 -> bm fastest (GEMM1: Wa panel L2-hot, q L3-hot);
// BMFAST=0 -> bn fastest (GEMM2).  LNA = log2(#blocks of the FASTEST axis).
template <bool RELU, int LNA, int ZSH, bool BMFAST>
__global__ __launch_bounds__(256, 2) void gemm128x256(
    const ushort* __restrict__ A, const ushort* __restrict__ B,
    ushort* __restrict__ Cout, const float* __restrict__ bias,
    int K,
    long sA_b, long sA_h, long sB_b, long sB_h, long sC_z, int ldc, long sBias_h)
{
    // K-loop: 3 bufs x [A: 8KB | B: 16KB].  Epilogue reuse: 4 waves x 18432 B.
    __shared__ __align__(16) char smem[3 * 24576];

    // bijective XCD swizzle (gridDim.x % 8 == 0 always)
    const int gid = blockIdx.x;
    const int per = (int)gridDim.x >> 3;
    const int w = (gid & 7) * per + (gid >> 3);
    const int z = w >> ZSH;
    const int rem = w & ((1 << ZSH) - 1);
    int bm0, bn0;
    if (BMFAST) { bm0 = (rem & ((1 << LNA) - 1)) * 128; bn0 = (rem >> LNA) * 256; }
    else        { bn0 = (rem & ((1 << LNA) - 1)) * 256; bm0 = (rem >> LNA) * 128; }

    const int b = z & 1, h = z >> 1;
    A += (size_t)b * sA_b + (size_t)h * sA_h;
    B += (size_t)b * sB_b + (size_t)h * sB_h;
    const float* biasp = bias ? bias + (size_t)h * sBias_h : nullptr;

    const int T = threadIdx.x;
    const int lane = T & 63, wc = T >> 6;           // 4 waves, each 128x64
    const int fr = lane & 15, fq = lane >> 4;
    const int laneoff = fr * 64 + ((fq * 16) ^ ((fr >> 3) << 5));   // swz read

    // staging: inst j writes LDS bytes [j*4096 + T*16 ..+16); derived mapping:
    // subtile s = j*4 + (T>>6), fr = (T>>2)&15, row = j*64 + (T>>6)*16 + fr,
    // col byte pre-swizzled (involution) to match the swizzled read.
    const int s_rowA = ((T >> 6) << 4) + ((T >> 2) & 15);
    const int s_csw  = ((T & 3) * 16) ^ (((T >> 5) & 1) << 5);
    const ushort* gA = A + (size_t)(bm0 + s_rowA) * K + (s_csw >> 1);
    const ushort* gB = B + (size_t)(bn0 + s_rowA) * K + (s_csw >> 1);

    const int nt = K >> 5;      // K-steps of 32

    // stage K-tile kt into buf sb: A 2 insts + B 4 insts (6/thread, 24KB total)
    auto stage = [&](int sb, int kt) {
        char* base = smem + sb * 24576;
#pragma unroll
        for (int j = 0; j < 2; ++j) {
            const ushort* src = gA + (size_t)j * 64 * K + (size_t)kt * 32;
            __builtin_amdgcn_global_load_lds(
                (const __attribute__((address_space(1))) void*)src,
                (__attribute__((address_space(3))) void*)(base + j * 4096 + (T << 4)),
                16, 0, 0);
        }
#pragma unroll
        for (int j = 0; j < 4; ++j) {
            const ushort* src = gB + (size_t)j * 64 * K + (size_t)kt * 32;
            __builtin_amdgcn_global_load_lds(
                (const __attribute__((address_space(1))) void*)src,
                (__attribute__((address_space(3))) void*)(base + 8192 + j * 4096 + (T << 4)),
                16, 0, 0);
        }
    };

    f32x4 acc[8][4];
#pragma unroll
    for (int m = 0; m < 8; ++m)
#pragma unroll
        for (int n = 0; n < 4; ++n)
#pragma unroll
            for (int j = 0; j < 4; ++j) acc[m][n][j] = 0.f;

    // one K-step (r10 schedule: pinned lgkmcnt(0), setprio, counted vmcnt(6))
    auto step = [&](int t, int rb, int sb, auto DOST, auto VM) {
        const char* base = smem + rb * 24576;
        const char* pA = base + laneoff;                    // all 128 A rows
        const char* pB = base + 8192 + wc * 4096 + laneoff; // wave's 64 cols
        short8 a[8], bb[4];
#pragma unroll
        for (int m = 0; m < 8; ++m) a[m] = *(const short8*)(pA + m * 1024);
#pragma unroll
        for (int n = 0; n < 4; ++n) bb[n] = *(const short8*)(pB + n * 1024);
        if constexpr (decltype(DOST)::v) stage(sb, t + 2);
        asm volatile("s_waitcnt lgkmcnt(0)" ::: "memory");
        __builtin_amdgcn_sched_barrier(0);
        __builtin_amdgcn_s_setprio(1);
#pragma unroll
        for (int m = 0; m < 8; ++m)
#pragma unroll
            for (int n = 0; n < 4; ++n)
                acc[m][n] = __builtin_amdgcn_mfma_f32_16x16x32_bf16(
                    a[m], bb[n], acc[m][n], 0, 0, 0);
        __builtin_amdgcn_s_setprio(0);
        __builtin_amdgcn_sched_barrier(0);
        constexpr int vm = decltype(VM)::v;
        if constexpr (vm == 6) asm volatile("s_waitcnt vmcnt(6)" ::: "memory");
        else if constexpr (vm == 0) asm volatile("s_waitcnt vmcnt(0)" ::: "memory");
        if constexpr (vm >= 0) asm volatile("s_barrier" ::: "memory");
    };

    // prologue: stage tiles 0,1 into bufs 0,1; wait tile 0 (12 -> 6 in flight)
    stage(0, 0); stage(1, 1);
    asm volatile("s_waitcnt vmcnt(6)" ::: "memory");
    asm volatile("s_barrier" ::: "memory");

    int rb = 0, sb = 2;
    for (int t = 0; t < nt - 2; ++t) {
        step(t, rb, sb, IC<1>{}, IC<6>{});
        rb = (rb == 2) ? 0 : rb + 1;
        sb = (sb == 2) ? 0 : sb + 1;
    }
    step(nt - 2, rb, sb, IC<0>{}, IC<0>{});     // drain last stage
    rb = (rb == 2) ? 0 : rb + 1;
    step(nt - 1, rb, sb, IC<0>{}, IC<-1>{});    // last MFMA, no barrier

    // ---- epilogue: LDS repack -> full-line 16 B/lane stores ----
    asm volatile("s_waitcnt vmcnt(0) lgkmcnt(0)" ::: "memory");
    __builtin_amdgcn_s_barrier();              // all waves done with K-loop LDS
    char* eb = smem + wc * 18432;              // 128 rows x 144 B per wave
    const int col0 = bn0 + wc * 64;
#pragma unroll
    for (int n = 0; n < 4; ++n) {
        const float bvv = biasp ? biasp[col0 + n * 16 + fr] : 0.f;
#pragma unroll
        for (int m = 0; m < 8; ++m) {
#pragma unroll
            for (int j = 0; j < 4; ++j) {
                float val = acc[m][n][j] + bvv;
                if (RELU) val = fmaxf(val, 0.f);
                *(ushort*)(eb + (m * 16 + fq * 4 + j) * 144 + (n * 16 + fr) * 2) = f2bf(val);
            }
        }
    }
    asm volatile("s_waitcnt lgkmcnt(0)" ::: "memory");   // per-wave region
    ushort* C = Cout + (size_t)z * sC_z;
    const int rl = lane >> 3, cb = lane & 7;
#pragma unroll
    for (int i = 0; i < 16; ++i) {
        short8 vv = *(const short8*)(eb + (i * 8 + rl) * 144 + cb * 16);
        *(short8*)(C + (size_t)(bm0 + i * 8 + rl) * ldc + col0 + cb * 8) = vv;
    }
}

// -------- fused LayerNorm + projection:  out = LN(agg) @ WpT^T + bp ----------
__global__ __launch_bounds__(256) void lnproj_kernel(const ushort* __restrict__ agg,
                                                     const ushort* __restrict__ WpT,
                                                     const float* __restrict__ gamma,
                                                     const float* __restrict__ beta,
                                                     const float* __restrict__ bp,
                                                     float* __restrict__ out,
                                                     int h_base) {
    const int z = blockIdx.y, b = z & 1, hg = h_base + (z >> 1);
    const int wid = threadIdx.x >> 6, lane = threadIdx.x & 63;
    const int fr = lane & 15, fq = lane >> 4;
    const int m0 = (blockIdx.x * 4 + wid) * 16;

    const ushort* Arow = agg + ((size_t)z * 2048 + m0 + fr) * 1024 + fq * 8;

    // pass 1: stats for row m0+fr
    float s = 0.f, s2 = 0.f;
    for (int kt = 0; kt < 32; ++kt) {
        short8 a = *(const short8*)(Arow + kt * 32);
#pragma unroll
        for (int j = 0; j < 8; ++j) { float x = bf2f((ushort)a[j]); s += x; s2 += x * x; }
    }
    s  += __shfl_xor(s, 16, 64);  s2 += __shfl_xor(s2, 16, 64);
    s  += __shfl_xor(s, 32, 64);  s2 += __shfl_xor(s2, 32, 64);
    const float mu  = s * (1.0f / 1024.0f);
    const float var = s2 * (1.0f / 1024.0f) - mu * mu;
    const float rs  = rsqrtf(fmaxf(var, 0.f) + 1e-5f);

    const ushort* Bbase = WpT + (size_t)hg * 64 * 1024 + (size_t)fr * 1024 + fq * 8;
    const float* gp = gamma + (size_t)hg * 1024 + fq * 8;
    const float* bt = beta  + (size_t)hg * 1024 + fq * 8;

    f32x4 acc[4];
#pragma unroll
    for (int n = 0; n < 4; ++n)
#pragma unroll
        for (int j = 0; j < 4; ++j) acc[n][j] = 0.f;

    for (int kt = 0; kt < 32; ++kt) {
        short8 a = *(const short8*)(Arow + kt * 32);
        float4 g0 = *(const float4*)(gp + kt * 32);
        float4 g1 = *(const float4*)(gp + kt * 32 + 4);
        float4 b0 = *(const float4*)(bt + kt * 32);
        float4 b1 = *(const float4*)(bt + kt * 32 + 4);
        const float gg[8] = {g0.x, g0.y, g0.z, g0.w, g1.x, g1.y, g1.z, g1.w};
        const float bb_[8] = {b0.x, b0.y, b0.z, b0.w, b1.x, b1.y, b1.z, b1.w};
        short8 an;
#pragma unroll
        for (int j = 0; j < 8; ++j) {
            float xn = (bf2f((ushort)a[j]) - mu) * rs * gg[j] + bb_[j];
            an[j] = (short)f2bf(xn);
        }
#pragma unroll
        for (int n = 0; n < 4; ++n) {
            short8 wv = *(const short8*)(Bbase + n * 16 * 1024 + kt * 32);
            acc[n] = __builtin_amdgcn_mfma_f32_16x16x32_bf16(an, wv, acc[n], 0, 0, 0);
        }
    }
#pragma unroll
    for (int n = 0; n < 4; ++n) {
        const int c = hg * 64 + n * 16 + fr;
        const float bvv = bp[c];
#pragma unroll
        for (int j = 0; j < 4; ++j)
            out[(size_t)b * 2048 * 1024 + (size_t)(m0 + fq * 4 + j) * 1024 + c] =
                acc[n][j] + bvv;
    }
}

extern "C" void kernel_launch(void* const* d_in, const int* in_sizes, int n_in,
                              void* d_out, int out_size, void* d_ws, size_t ws_size,
                              hipStream_t stream) {
    const float* v     = (const float*)d_in[0];
    const float* q     = (const float*)d_in[1];
    const float* Wa    = (const float*)d_in[2];
    const float* ba    = (const float*)d_in[3];
    const float* gamma = (const float*)d_in[4];
    const float* beta  = (const float*)d_in[5];
    const float* Wp    = (const float*)d_in[6];
    const float* bp    = (const float*)d_in[7];
    float* out = (float*)d_out;

    const size_t MB = 1ull << 20;
    char* ws = (char*)d_ws;
    ushort* qbf = (ushort*)(ws);                 //  8 MiB
    ushort* vT  = (ushort*)(ws + 8 * MB);        //  8 MiB
    ushort* WpT = (ushort*)(ws + 16 * MB);       //  2 MiB
    int NH = 1;
    {
        const int cands[5] = {16, 8, 4, 2, 1};
        for (int i = 0; i < 5; ++i) {
            if ((size_t)(18 + 28 * cands[i]) * MB <= ws_size) { NH = cands[i]; break; }
        }
    }
    ushort* WaT_c  = (ushort*)(ws + 18 * MB);
    ushort* attn_c = (ushort*)(ws + (18 + (size_t)4 * NH) * MB);
    ushort* agg_c  = (ushort*)(ws + (18 + (size_t)20 * NH) * MB);

    dim3 tb(32, 8);
    cast_bf16<<<4096, 256, 0, stream>>>(q, qbf, BATCH * LQ * DMODEL);
    transpose_cast<<<dim3(DMODEL / 32, LV / 32, BATCH), tb, 0, stream>>>(v, vT, LV, DMODEL);
    transpose_cast<<<dim3(HEAD_DIM / 32, DMODEL / 32, N_HEAD), tb, 0, stream>>>(Wp, WpT, DMODEL, HEAD_DIM);

    for (int h0 = 0; h0 < N_HEAD; h0 += NH) {
        transpose_cast<<<dim3(LV / 32, DMODEL / 32, NH), tb, 0, stream>>>(
            Wa + (size_t)h0 * DMODEL * LV, WaT_c, DMODEL, LV);

        // GEMM1: attn[z] = relu(q[b] @ WaT[h]^T + ba), M=2048 N=2048 K=1024
        // 16 bm (fastest) x 8 bn x z; bm-fastest keeps Wa panel L2-hot, q L3-hot
        gemm128x256<true, 4, 7, true><<<128 * NH * 2, 256, 0, stream>>>(
            qbf, WaT_c, attn_c, ba + (size_t)h0 * LV, DMODEL,
            (long)LQ * DMODEL, 0L,
            0L, (long)LV * DMODEL,
            (long)LQ * LV, LV, (long)LV);

        // GEMM2: agg[z] = attn[z] @ vT[b]^T, M=2048 N=1024 K=2048
        // 4 bn (fastest) x 16 bm x z; vT is L2-resident, attn panels L3-hot
        gemm128x256<false, 2, 6, false><<<64 * NH * 2, 256, 0, stream>>>(
            attn_c, vT, agg_c, nullptr, LV,
            (long)LQ * LV, (long)2 * LQ * LV,
            (long)DMODEL * LV, 0L,
            (long)LQ * DMODEL, DMODEL, 0L);

        // fused LayerNorm + projection + head concat -> d_out (f32)
        lnproj_kernel<<<dim3(LQ / 64, NH * 2), 256, 0, stream>>>(
            agg_c, WpT, gamma, beta, bp, out, h0);
    }
}